// Round 2
// baseline (31.141 us; speedup 1.0000x reference)
//
#include <hip/hip_runtime.h>
#include <math.h>

#define KCL 64
#define NPTS 32768
#define NBATCH 8
#define BLOCK 256

// ---------------------------------------------------------------------------
// Kernel 1: fold rotation/scale/center/constant into a 16-float record per
// (b,k) in workspace. M = diag(1/s) * R^T, pre-scaled by sqrt(0.5*log2(e)) so
// that weights = exp(-0.5*dist2) == exp2(-(|M(p-?)|^2)) -> single v_exp_f32.
// Record layout (16 floats, 64B): m00..m22 [0..8], q0..q2 [9..11], const [12].
// Thread 0 also zeroes the output accumulator (replaces a memset dispatch).
// ---------------------------------------------------------------------------
__global__ __launch_bounds__(NBATCH * KCL) void fold_params_kernel(
    const float* __restrict__ constants,  // B*K
    const float* __restrict__ scales,     // B*K*3
    const float* __restrict__ rotations,  // B*K*3
    const float* __restrict__ centers,    // B*K*3
    float*       __restrict__ ws,         // B*K*16 floats
    float*       __restrict__ out)
{
    const int t = threadIdx.x;            // t = b*64 + k, 0..511
    if (t == 0) out[0] = 0.0f;

    const float rx = rotations[3 * t + 0];
    const float ry = rotations[3 * t + 1];
    const float rz = rotations[3 * t + 2];
    const float sx = sinf(rx), cx = cosf(rx);
    const float sy = sinf(ry), cy = cosf(ry);
    const float sz = sinf(rz), cz = cosf(rz);

    // R row-major per reference
    float R[3][3];
    R[0][0] = cz * cy; R[0][1] = cz * sy * sx - sz * cx; R[0][2] = cz * sy * cx + sz * sx;
    R[1][0] = sz * cy; R[1][1] = sz * sy * sx + cz * cx; R[1][2] = sz * sy * cx - cz * sx;
    R[2][0] = -sy;     R[2][1] = cy * sx;                R[2][2] = cy * cx;

    const float SC = 0.84932184f;         // sqrt(0.5 * log2(e))
    const float i0 = SC / scales[3 * t + 0];
    const float i1 = SC / scales[3 * t + 1];
    const float i2 = SC / scales[3 * t + 2];
    const float inv[3] = {i0, i1, i2};

    const float c0 = centers[3 * t + 0];
    const float c1 = centers[3 * t + 1];
    const float c2 = centers[3 * t + 2];

    float* rec = ws + t * 16;
    #pragma unroll
    for (int i = 0; i < 3; ++i) {
        // local_i = sum_j R[j][i] * diff_j  ->  m_{i,j} = R[j][i] * inv_i
        const float m0 = R[0][i] * inv[i];
        const float m1 = R[1][i] * inv[i];
        const float m2 = R[2][i] * inv[i];
        rec[i * 3 + 0] = m0;
        rec[i * 3 + 1] = m1;
        rec[i * 3 + 2] = m2;
        rec[9 + i] = m0 * c0 + m1 * c1 + m2 * c2;   // q_i = (M c)_i
    }
    rec[12] = constants[t];
    rec[13] = 0.0f; rec[14] = 0.0f; rec[15] = 0.0f;
}

// ---------------------------------------------------------------------------
// Kernel 2: per-point loss. Cluster records are read with wave-uniform
// indices -> scalar loads (s_load_dwordx16) through the constant cache;
// inner loop is pure VALU (9 fma + d2 + exp2 + acc per cluster).
// ---------------------------------------------------------------------------
__global__ __launch_bounds__(BLOCK) void point_loss_kernel(
    const float4* __restrict__ pts,   // B*N float4 (x,y,z,sdf)
    const float*  __restrict__ cl,    // B*K*16 folded records
    float*        __restrict__ out)
{
    __shared__ float wave_sums[BLOCK / 64];

    const int b   = blockIdx.x >> 7;                       // /128 blocks per batch
    const int idx = (blockIdx.x << 8) + threadIdx.x;       // global point id
    const float4 p = pts[idx];
    const float px = p.x, py = p.y, pz = p.z;

    const float* cb = cl + (b << 10);                      // b*K*16

    float sdf = 0.0f;
    #pragma unroll 4
    for (int k = 0; k < KCL; ++k) {
        const float* c = cb + (k << 4);
        const float q0 = c[9], q1 = c[10], q2 = c[11];
        const float vx = fmaf(c[0], px, fmaf(c[1], py, fmaf(c[2], pz, -q0)));
        const float vy = fmaf(c[3], px, fmaf(c[4], py, fmaf(c[5], pz, -q1)));
        const float vz = fmaf(c[6], px, fmaf(c[7], py, fmaf(c[8], pz, -q2)));
        const float d2 = fmaf(vx, vx, fmaf(vy, vy, vz * vz));
        sdf = fmaf(c[12], exp2f(-d2), sdf);                // v_exp_f32, neg is free
    }

    // loss term
    const float class_gt = (p.w > 0.0f) ? 1.0f : 0.0f;
    const float z = 100.0f * (sdf + 0.07f);                // SOFT*(sdf - LEVEL_SET)
    const float class_pred = 1.0f / (1.0f + exp2f(-1.44269504f * z));
    const float w = class_gt + 10.0f * (1.0f - class_gt);
    const float d = class_gt - class_pred;
    float term = w * d * d;

    // wave (64) shuffle reduce, then cross-wave via LDS
    #pragma unroll
    for (int off = 32; off > 0; off >>= 1)
        term += __shfl_down(term, off, 64);

    const int wave = threadIdx.x >> 6;
    const int lane = threadIdx.x & 63;
    if (lane == 0) wave_sums[wave] = term;
    __syncthreads();

    if (threadIdx.x == 0) {
        float s = 0.0f;
        #pragma unroll
        for (int i = 0; i < BLOCK / 64; ++i) s += wave_sums[i];
        atomicAdd(out, s * (1.0f / (NBATCH * (float)NPTS)));
    }
}

extern "C" void kernel_launch(void* const* d_in, const int* in_sizes, int n_in,
                              void* d_out, int out_size, void* d_ws, size_t ws_size,
                              hipStream_t stream) {
    const float4* pts       = (const float4*)d_in[0];
    const float*  constants = (const float*)d_in[1];
    const float*  scales    = (const float*)d_in[2];
    const float*  rotations = (const float*)d_in[3];
    const float*  centers   = (const float*)d_in[4];
    float* out = (float*)d_out;
    float* ws  = (float*)d_ws;

    fold_params_kernel<<<1, NBATCH * KCL, 0, stream>>>(
        constants, scales, rotations, centers, ws, out);

    const int nblocks = NBATCH * (NPTS / BLOCK);   // 1024
    point_loss_kernel<<<nblocks, BLOCK, 0, stream>>>(pts, ws, out);
}

// Round 3
// 16.310 us; speedup vs baseline: 1.9093x; 1.9093x over previous
//
#include <hip/hip_runtime.h>
#include <math.h>

#define KCL 64
#define NPTS 32768
#define NBATCH 8
#define BLOCK 256
#define PPT 2                       // points per thread
#define PTS_PER_BLOCK (BLOCK * PPT) // 512
#define NBLOCKS (NBATCH * NPTS / PTS_PER_BLOCK)      // 512
#define BLOCKS_PER_B (NPTS / PTS_PER_BLOCK)          // 64

// ---------------------------------------------------------------------------
// Main kernel: per-block fold of this batch's 64 cluster records into LDS
// (one wave, once), then P=2 points per thread against all 64 clusters.
// Records padded to 16 floats -> 4x ds_read_b128 per cluster, wave-uniform
// broadcast (conflict-free). Partial sums go to d_ws -- NO global atomics.
//
// Record float4 layout: [m00 m01 m02 m10][m11 m12 m20 m21][m22 q0 q1 q2][c . . .]
// M = diag(sqrt(0.5*log2 e)/s) * R^T, q = M*center, so
// weight = const * exp2(-|M p - q|^2).
// ---------------------------------------------------------------------------
__global__ __launch_bounds__(BLOCK) void point_loss_kernel(
    const float4* __restrict__ pts,   // B*N float4 (x,y,z,sdf)
    const float*  __restrict__ constants,
    const float*  __restrict__ scales,
    const float*  __restrict__ rotations,
    const float*  __restrict__ centers,
    float*        __restrict__ partials)  // NBLOCKS floats in d_ws
{
    __shared__ float4 cl4[KCL][4];
    __shared__ float wave_sums[BLOCK / 64];

    const int tid = threadIdx.x;
    const int b   = blockIdx.x / BLOCKS_PER_B;

    // ---- fold phase: one wave computes 64 records ----
    if (tid < KCL) {
        const int base = b * KCL + tid;
        const float rx = rotations[3 * base + 0];
        const float ry = rotations[3 * base + 1];
        const float rz = rotations[3 * base + 2];
        const float sx = sinf(rx), cx = cosf(rx);
        const float sy = sinf(ry), cy = cosf(ry);
        const float sz = sinf(rz), cz = cosf(rz);

        float R[3][3];
        R[0][0] = cz * cy; R[0][1] = cz * sy * sx - sz * cx; R[0][2] = cz * sy * cx + sz * sx;
        R[1][0] = sz * cy; R[1][1] = sz * sy * sx + cz * cx; R[1][2] = sz * sy * cx - cz * sx;
        R[2][0] = -sy;     R[2][1] = cy * sx;                R[2][2] = cy * cx;

        const float SC = 0.84932184f;  // sqrt(0.5 * log2(e))
        const float inv[3] = { SC / scales[3 * base + 0],
                               SC / scales[3 * base + 1],
                               SC / scales[3 * base + 2] };
        const float c0 = centers[3 * base + 0];
        const float c1 = centers[3 * base + 1];
        const float c2 = centers[3 * base + 2];

        float rec[13];
        #pragma unroll
        for (int i = 0; i < 3; ++i) {
            const float m0 = R[0][i] * inv[i];
            const float m1 = R[1][i] * inv[i];
            const float m2 = R[2][i] * inv[i];
            rec[i * 3 + 0] = m0;
            rec[i * 3 + 1] = m1;
            rec[i * 3 + 2] = m2;
            rec[9 + i] = m0 * c0 + m1 * c1 + m2 * c2;
        }
        cl4[tid][0] = make_float4(rec[0], rec[1], rec[2], rec[3]);
        cl4[tid][1] = make_float4(rec[4], rec[5], rec[6], rec[7]);
        cl4[tid][2] = make_float4(rec[8], rec[9], rec[10], rec[11]);
        cl4[tid][3] = make_float4(constants[base], 0.0f, 0.0f, 0.0f);
    }
    __syncthreads();

    // ---- point phase: P=2 points per thread ----
    const int n0 = (blockIdx.x % BLOCKS_PER_B) * PTS_PER_BLOCK + tid;
    const float4 p0 = pts[b * NPTS + n0];
    const float4 p1 = pts[b * NPTS + n0 + BLOCK];

    float sdf0 = 0.0f, sdf1 = 0.0f;
    #pragma unroll 4
    for (int k = 0; k < KCL; ++k) {
        const float4 A = cl4[k][0];
        const float4 Bv = cl4[k][1];
        const float4 C = cl4[k][2];
        const float cst = cl4[k][3].x;

        float vx = fmaf(A.x, p0.x, fmaf(A.y, p0.y, fmaf(A.z, p0.z, -C.y)));
        float vy = fmaf(A.w, p0.x, fmaf(Bv.x, p0.y, fmaf(Bv.y, p0.z, -C.z)));
        float vz = fmaf(Bv.z, p0.x, fmaf(Bv.w, p0.y, fmaf(C.x, p0.z, -C.w)));
        float d2 = fmaf(vx, vx, fmaf(vy, vy, vz * vz));
        sdf0 = fmaf(cst, __builtin_amdgcn_exp2f(-d2), sdf0);

        vx = fmaf(A.x, p1.x, fmaf(A.y, p1.y, fmaf(A.z, p1.z, -C.y)));
        vy = fmaf(A.w, p1.x, fmaf(Bv.x, p1.y, fmaf(Bv.y, p1.z, -C.z)));
        vz = fmaf(Bv.z, p1.x, fmaf(Bv.w, p1.y, fmaf(C.x, p1.z, -C.w)));
        d2 = fmaf(vx, vx, fmaf(vy, vy, vz * vz));
        sdf1 = fmaf(cst, __builtin_amdgcn_exp2f(-d2), sdf1);
    }

    // loss terms
    float term;
    {
        const float gt0 = (p0.w > 0.0f) ? 1.0f : 0.0f;
        const float z0 = 100.0f * (sdf0 + 0.07f);
        const float pr0 = 1.0f / (1.0f + __builtin_amdgcn_exp2f(-1.44269504f * z0));
        const float w0 = gt0 + 10.0f * (1.0f - gt0);
        const float d0 = gt0 - pr0;

        const float gt1 = (p1.w > 0.0f) ? 1.0f : 0.0f;
        const float z1 = 100.0f * (sdf1 + 0.07f);
        const float pr1 = 1.0f / (1.0f + __builtin_amdgcn_exp2f(-1.44269504f * z1));
        const float w1 = gt1 + 10.0f * (1.0f - gt1);
        const float d1 = gt1 - pr1;

        term = w0 * d0 * d0 + w1 * d1 * d1;
    }

    // wave (64) shuffle reduce, then cross-wave via LDS
    #pragma unroll
    for (int off = 32; off > 0; off >>= 1)
        term += __shfl_down(term, off, 64);

    const int wave = tid >> 6;
    if ((tid & 63) == 0) wave_sums[wave] = term;
    __syncthreads();

    if (tid == 0) {
        float s = 0.0f;
        #pragma unroll
        for (int i = 0; i < BLOCK / 64; ++i) s += wave_sums[i];
        partials[blockIdx.x] = s;
    }
}

// ---------------------------------------------------------------------------
// Final reduce: 1 block, 256 threads, sums NBLOCKS=512 partials.
// ---------------------------------------------------------------------------
__global__ __launch_bounds__(256) void reduce_kernel(
    const float* __restrict__ partials,
    float*       __restrict__ out)
{
    __shared__ float wave_sums[4];
    const int tid = threadIdx.x;
    float s = partials[tid] + partials[tid + 256];

    #pragma unroll
    for (int off = 32; off > 0; off >>= 1)
        s += __shfl_down(s, off, 64);

    if ((tid & 63) == 0) wave_sums[tid >> 6] = s;
    __syncthreads();

    if (tid == 0) {
        float t = wave_sums[0] + wave_sums[1] + wave_sums[2] + wave_sums[3];
        out[0] = t * (1.0f / (NBATCH * (float)NPTS));
    }
}

extern "C" void kernel_launch(void* const* d_in, const int* in_sizes, int n_in,
                              void* d_out, int out_size, void* d_ws, size_t ws_size,
                              hipStream_t stream) {
    const float4* pts       = (const float4*)d_in[0];
    const float*  constants = (const float*)d_in[1];
    const float*  scales    = (const float*)d_in[2];
    const float*  rotations = (const float*)d_in[3];
    const float*  centers   = (const float*)d_in[4];
    float* out      = (float*)d_out;
    float* partials = (float*)d_ws;

    point_loss_kernel<<<NBLOCKS, BLOCK, 0, stream>>>(
        pts, constants, scales, rotations, centers, partials);
    reduce_kernel<<<1, 256, 0, stream>>>(partials, out);
}